// Round 2
// baseline (45313.812 us; speedup 1.0000x reference)
//
#include <hip/hip_runtime.h>
#include <hip/hip_bf16.h>
#include <hip/hip_cooperative_groups.h>
#include <cstdint>
#include <cstddef>

namespace cg = cooperative_groups;

// SimpleXLSTM persistent-kernel round 2.
// 2-layer LSTM (B=128, T=512, IN=512, H=1024) + sigmoid head.
// One cooperative kernel, 256 blocks (1/CU) x 256 threads (4 waves).
// Block owns 16 interleaved output cols (= 4 hidden units x 4 gates) of BOTH
// layers; weights live in LDS (112 KB) in MFMA-fragment order for the whole
// sequence. Phase p computes layer0(t=p) and layer1(t=p-1) -> one grid.sync
// per phase (513 barriers total).

#define BATCH 128
#define SEQ   512
#define INP   512
#define HID   1024
#define NCOL  4096
#define NB    256    // persistent blocks
#define KS0   48     // k-steps layer0 (1536/32)
#define KS1   64     // k-steps layer1 (2048/32)

typedef __bf16 bf16x8 __attribute__((ext_vector_type(8)));
typedef float  f32x4  __attribute__((ext_vector_type(4)));
typedef unsigned int u32x4 __attribute__((ext_vector_type(4)));

// ---- dynamic LDS layout (bytes) ----
#define OFF_W0   0        // 48*4*16*16 = 49152
#define OFF_W1   49152    // 64*4*16*16 = 65536
#define OFF_ZP   114688   // 4*128*17*4 = 34816
#define OFF_C0   149504   // 128*4*4    = 2048
#define OFF_C1   151552   // 2048
#define OFF_B0   153600   // 16*4 = 64
#define OFF_B1   153664   // 64
#define LDS_TOTAL 153728

__device__ __forceinline__ bf16x8 load_bf16x8(const __hip_bfloat16* p) {
    u32x4 u = *reinterpret_cast<const u32x4*>(p);
    return __builtin_bit_cast(bf16x8, u);
}
__device__ __forceinline__ f32x4 mfma16(bf16x8 a, bf16x8 b, f32x4 c) {
    return __builtin_amdgcn_mfma_f32_16x16x32_bf16(a, b, c, 0, 0, 0);
}
__device__ __forceinline__ float sigmoidf_(float x) {
    return 1.0f / (1.0f + expf(-x));
}

// ---------------------------------------------------------------------------
// Prep: W [K][4096] fp32 -> F fragment-ordered bf16.
// F chunk index = ((nb*Ks + ks)*4 + kg)*16 + cl  holds 8 bf16:
//   W[k = ks*32 + kg*8 + j][c]  where interleaved row r = nb*16+cl,
//   c = (r&3)*1024 + (r>>2)   (gate-major orig col -> unit-interleaved row).
// ---------------------------------------------------------------------------
template<int Ks>
__global__ __launch_bounds__(1024)
void pack_frag_kernel(const float* __restrict__ W, __hip_bfloat16* __restrict__ F)
{
    __shared__ float tile[32][33];
    const int k0 = blockIdx.x * 32;
    const int c0 = blockIdx.y * 32;
    const int tx = threadIdx.x & 31, ty = threadIdx.x >> 5;
    tile[ty][tx] = W[(size_t)(k0 + ty) * NCOL + (c0 + tx)];
    __syncthreads();
    const int cL  = threadIdx.x >> 5;        // 0..31
    const int kgw = (threadIdx.x >> 3) & 3;  // 0..3
    const int j   = threadIdx.x & 7;         // 0..7
    const int c   = c0 + cL;
    const int r   = (c & 1023) * 4 + (c >> 10);
    const int nb2 = r >> 4, cl = r & 15;
    const int ks  = k0 >> 5;
    const size_t chunk = ((size_t)(nb2 * Ks + ks) * 4 + kgw) * 16 + cl;
    F[chunk * 8 + j] = __float2bfloat16(tile[kgw * 8 + j][cL]);
}

__global__ void bias_reorder_kernel(const float* __restrict__ b0,
                                    const float* __restrict__ b1,
                                    float* __restrict__ b0r,
                                    float* __restrict__ b1r)
{
    int i = blockIdx.x * blockDim.x + threadIdx.x;
    if (i >= 2 * NCOL) return;
    const float* src = (i < NCOL) ? b0 : b1;
    float*       dst = (i < NCOL) ? b0r : b1r;
    int c = i & (NCOL - 1);
    dst[(c & 1023) * 4 + (c >> 10)] = src[c];
}

// ---------------------------------------------------------------------------
// Persistent kernel
// ---------------------------------------------------------------------------
#define B0FRAG(ks) (*(const bf16x8*)(lW0 + (size_t)((((ks)*4 + kg)*16 + lm) * 8)))
#define B1FRAG(ks) (*(const bf16x8*)(lW1 + (size_t)((((ks)*4 + kg)*16 + lm) * 8)))

#define LOAD0_X(i, A, B) { \
    const int ks_ = w + 4*(i); const int kk_ = ks_*32 + kg*8; \
    (B) = B0FRAG(ks_); \
    _Pragma("unroll") for (int m_ = 0; m_ < 8; ++m_) { \
        const float* xr_ = xbase + (size_t)m_ * (16 * SEQ * INP) + kk_; \
        f32x4 lo_ = *(const f32x4*)xr_; f32x4 hi_ = *(const f32x4*)(xr_ + 4); \
        bf16x8 v_; \
        v_[0]=(__bf16)lo_[0]; v_[1]=(__bf16)lo_[1]; v_[2]=(__bf16)lo_[2]; v_[3]=(__bf16)lo_[3]; \
        v_[4]=(__bf16)hi_[0]; v_[5]=(__bf16)hi_[1]; v_[6]=(__bf16)hi_[2]; v_[7]=(__bf16)hi_[3]; \
        (A)[m_] = v_; } }

#define LOAD0_H(i, A, B) { \
    const int ks_ = w + 4*(i); const int hk_ = ks_*32 + kg*8 - INP; \
    (B) = B0FRAG(ks_); \
    _Pragma("unroll") for (int m_ = 0; m_ < 8; ++m_) \
        (A)[m_] = load_bf16x8(h0prev + (size_t)(m_*16 + lm) * HID + hk_); }

#define LOAD1_A(i, A, B) { \
    const int ks_ = w + 4*(i); \
    (B) = B1FRAG(ks_); \
    const __hip_bfloat16* ap_ = ((i) < 8) \
        ? (h0prev + (size_t)lm * HID + (ks_*32 + kg*8)) \
        : (h1prev + (size_t)lm * HID + ((ks_-32)*32 + kg*8)); \
    _Pragma("unroll") for (int m_ = 0; m_ < 8; ++m_) \
        (A)[m_] = load_bf16x8(ap_ + (size_t)m_ * (16 * HID)); }

#define STORE_ZP() { \
    float* zp_ = zpart + (size_t)(w * 128) * 17 + lm; \
    _Pragma("unroll") for (int m_ = 0; m_ < 8; ++m_) \
        _Pragma("unroll") for (int r_ = 0; r_ < 4; ++r_) \
            zp_[(m_*16 + kg*4 + r_) * 17] = acc[m_][r_]; }

__global__ __launch_bounds__(256, 1)
void lstm_persistent(const float* __restrict__ x,
                     const __hip_bfloat16* __restrict__ F0,
                     const __hip_bfloat16* __restrict__ F1,
                     const float* __restrict__ b0r,
                     const float* __restrict__ b1r,
                     const float* __restrict__ Wout,
                     const float* __restrict__ bout,
                     __hip_bfloat16* __restrict__ h0,   // 2 slots of [128][1024]
                     __hip_bfloat16* __restrict__ h1,   // 2 slots
                     float* __restrict__ out)
{
    extern __shared__ char smem[];
    __hip_bfloat16* lW0 = (__hip_bfloat16*)(smem + OFF_W0);
    __hip_bfloat16* lW1 = (__hip_bfloat16*)(smem + OFF_W1);
    float* zpart = (float*)(smem + OFF_ZP);
    float* c0s   = (float*)(smem + OFF_C0);
    float* c1s   = (float*)(smem + OFF_C1);
    float* bias0 = (float*)(smem + OFF_B0);
    float* bias1 = (float*)(smem + OFF_B1);

    const int tid  = threadIdx.x;
    const int lane = tid & 63;
    const int w    = tid >> 6;
    const int nb   = blockIdx.x;
    const int lm   = lane & 15;
    const int kg   = lane >> 4;
    const int HS   = BATCH * HID;

    // ---- one-time: weights -> LDS (linear copy, fragment order), bias, c=0
    {
        const u32x4* s0 = (const u32x4*)(F0 + (size_t)nb * (KS0 * 64 * 8));
        u32x4*       d0 = (u32x4*)lW0;
        for (int i = tid; i < KS0 * 64; i += 256) d0[i] = s0[i];
        const u32x4* s1 = (const u32x4*)(F1 + (size_t)nb * (KS1 * 64 * 8));
        u32x4*       d1 = (u32x4*)lW1;
        for (int i = tid; i < KS1 * 64; i += 256) d1[i] = s1[i];
        if (tid < 16) { bias0[tid] = b0r[nb * 16 + tid]; bias1[tid] = b1r[nb * 16 + tid]; }
        for (int i = tid; i < 512; i += 256) { c0s[i] = 0.f; c1s[i] = 0.f; }
    }
    __syncthreads();

    cg::grid_group grid = cg::this_grid();

    for (int p = 0; p <= SEQ; ++p) {
        const int sc = p & 1, sp = sc ^ 1;
        const __hip_bfloat16* h0prev = h0 + (size_t)sp * HS;  // h0(p-1)
        const __hip_bfloat16* h1prev = h1 + (size_t)sc * HS;  // h1(p-2)

        // ================= layer 0, t = p =================
        if (p < SEQ) {
            const int t = p;
            const float* xbase = x + ((size_t)lm * SEQ + t) * INP;
            f32x4 acc[8];
            #pragma unroll
            for (int m = 0; m < 8; ++m) acc[m] = f32x4{0.f, 0.f, 0.f, 0.f};
            bf16x8 aC[8], aN[8], bC, bN;
            LOAD0_X(0, aC, bC);
            #pragma unroll
            for (int i = 0; i < 12; ++i) {
                if (i < 3)       { LOAD0_X(i + 1, aN, bN); }
                else if (i < 11) { LOAD0_H(i + 1, aN, bN); }
                #pragma unroll
                for (int m = 0; m < 8; ++m) acc[m] = mfma16(aC[m], bC, acc[m]);
                if (i < 11) {
                    bC = bN;
                    #pragma unroll
                    for (int m = 0; m < 8; ++m) aC[m] = aN[m];
                }
            }
            STORE_ZP();
        }
        __syncthreads();

        if (p < SEQ) {  // gates layer 0 -> h0[sc]
            __hip_bfloat16* hw = h0 + (size_t)sc * HS;
            for (int it = tid; it < 512; it += 256) {
                const int bl = it >> 2, u = it & 3;
                float g4[4];
                #pragma unroll
                for (int gg = 0; gg < 4; ++gg) {
                    float s = bias0[4 * u + gg];
                    #pragma unroll
                    for (int ww = 0; ww < 4; ++ww)
                        s += zpart[(size_t)(ww * 128 + bl) * 17 + 4 * u + gg];
                    g4[gg] = s;
                }
                const float cold = c0s[bl * 4 + u];
                const float cn = sigmoidf_(g4[0]) * cold + sigmoidf_(g4[1]) * tanhf(g4[3]);
                const float hn = sigmoidf_(g4[2]) * tanhf(cn);
                c0s[bl * 4 + u] = cn;
                hw[(size_t)bl * HID + nb * 4 + u] = __float2bfloat16(hn);
            }
        }
        __syncthreads();   // zpart reuse guard

        // ================= layer 1, t = p-1 =================
        if (p >= 1) {
            f32x4 acc[8];
            #pragma unroll
            for (int m = 0; m < 8; ++m) acc[m] = f32x4{0.f, 0.f, 0.f, 0.f};
            bf16x8 aC[8], aN[8], bC, bN;
            LOAD1_A(0, aC, bC);
            #pragma unroll
            for (int i = 0; i < 16; ++i) {
                if (i < 15) { LOAD1_A(i + 1, aN, bN); }
                #pragma unroll
                for (int m = 0; m < 8; ++m) acc[m] = mfma16(aC[m], bC, acc[m]);
                if (i < 15) {
                    bC = bN;
                    #pragma unroll
                    for (int m = 0; m < 8; ++m) aC[m] = aN[m];
                }
            }
            STORE_ZP();
        }
        __syncthreads();

        if (p >= 1) {  // gates layer 1 -> h1[sp]  (t = p-1)
            __hip_bfloat16* hw = h1 + (size_t)sp * HS;
            for (int it = tid; it < 512; it += 256) {
                const int bl = it >> 2, u = it & 3;
                float g4[4];
                #pragma unroll
                for (int gg = 0; gg < 4; ++gg) {
                    float s = bias1[4 * u + gg];
                    #pragma unroll
                    for (int ww = 0; ww < 4; ++ww)
                        s += zpart[(size_t)(ww * 128 + bl) * 17 + 4 * u + gg];
                    g4[gg] = s;
                }
                const float cold = c1s[bl * 4 + u];
                const float cn = sigmoidf_(g4[0]) * cold + sigmoidf_(g4[1]) * tanhf(g4[3]);
                const float hn = sigmoidf_(g4[2]) * tanhf(cn);
                c1s[bl * 4 + u] = cn;
                hw[(size_t)bl * HID + nb * 4 + u] = __float2bfloat16(hn);
            }
        }
        __threadfence();
        grid.sync();
    }

    // ---- head: out[b] = sigmoid(h1(511) . Wout + bout); h1(511) in slot 1
    if (nb == 0 && tid < BATCH) {
        const __hip_bfloat16* hr = h1 + (size_t)1 * HS + (size_t)tid * HID;
        float acc = 0.f;
        for (int k2 = 0; k2 < HID; k2 += 8) {
            bf16x8 v = load_bf16x8(hr + k2);
            #pragma unroll
            for (int j = 0; j < 8; ++j)
                acc += (float)v[j] * Wout[k2 + j];
        }
        out[tid] = 1.f / (1.f + expf(-(acc + bout[0])));
    }
}

// ---------------------------------------------------------------------------
extern "C" void kernel_launch(void* const* d_in, const int* in_sizes, int n_in,
                              void* d_out, int out_size, void* d_ws, size_t ws_size,
                              hipStream_t stream)
{
    const float* x    = (const float*)d_in[0];   // [128][512][512]
    const float* W0   = (const float*)d_in[1];   // [1536][4096]
    const float* b0   = (const float*)d_in[2];   // [4096]
    const float* W1   = (const float*)d_in[3];   // [2048][4096]
    const float* b1   = (const float*)d_in[4];   // [4096]
    const float* Wout = (const float*)d_in[5];   // [1024]
    const float* bout = (const float*)d_in[6];   // [1]
    float* out = (float*)d_out;

    char* ws = (char*)d_ws;
    const size_t OFF_F0  = 0;            // 4096*1536*2 = 12,582,912
    const size_t OFF_F1  = 12582912;     // 4096*2048*2 = 16,777,216
    const size_t OFF_B0R = 29360128;     // 16,384
    const size_t OFF_B1R = 29376512;     // 16,384
    const size_t OFF_H0  = 29392896;     // 2*128*1024*2 = 524,288
    const size_t OFF_H1  = 29917184;     // 524,288   (end: 30,441,472)

    __hip_bfloat16* F0 = (__hip_bfloat16*)(ws + OFF_F0);
    __hip_bfloat16* F1 = (__hip_bfloat16*)(ws + OFF_F1);
    float* b0r = (float*)(ws + OFF_B0R);
    float* b1r = (float*)(ws + OFF_B1R);
    __hip_bfloat16* h0 = (__hip_bfloat16*)(ws + OFF_H0);
    __hip_bfloat16* h1 = (__hip_bfloat16*)(ws + OFF_H1);

    // zero recurrent h buffers (c-state lives in LDS)
    hipMemsetAsync(ws + OFF_H0, 0, 1048576, stream);

    pack_frag_kernel<KS0><<<dim3(48, 128), 1024, 0, stream>>>(W0, F0);
    pack_frag_kernel<KS1><<<dim3(64, 128), 1024, 0, stream>>>(W1, F1);
    bias_reorder_kernel<<<32, 256, 0, stream>>>(b0, b1, b0r, b1r);

    hipFuncSetAttribute((const void*)lstm_persistent,
                        hipFuncAttributeMaxDynamicSharedMemorySize, LDS_TOTAL);

    void* args[] = {(void*)&x, (void*)&F0, (void*)&F1, (void*)&b0r, (void*)&b1r,
                    (void*)&Wout, (void*)&bout, (void*)&h0, (void*)&h1, (void*)&out};
    hipLaunchCooperativeKernel((void*)lstm_persistent, dim3(NB), dim3(256),
                               args, LDS_TOTAL, stream);
}

// Round 3
// 28849.585 us; speedup vs baseline: 1.5707x; 1.5707x over previous
//
#include <hip/hip_runtime.h>
#include <hip/hip_bf16.h>
#include <cstdint>
#include <cstddef>

// SimpleXLSTM persistent-kernel round 3.
// 2-layer LSTM (B=128, T=512, IN=512, H=1024) + sigmoid head.
// One cooperative kernel, 256 blocks x 1024 threads (16 waves = 4/SIMD).
// Block owns 16 interleaved cols (4 units x 4 gates) of both layers; weights
// in LDS. Custom L3-counter grid barrier (relaxed add + poll, one wbl2/inv
// per block per phase). Waves: 4 k-groups x 4 m-groups, 3-stage prefetch,
// LDS atomicAdd z-reduction, fused 2-layer gates.

#define BATCH 128
#define SEQ   512
#define INP   512
#define HID   1024
#define NCOL  4096
#define NB    256
#define KS0   48     // k-steps layer0 (1536/32)
#define KS1   64     // k-steps layer1 (2048/32)

typedef __bf16 bf16x8 __attribute__((ext_vector_type(8)));
typedef float  f32x4  __attribute__((ext_vector_type(4)));
typedef unsigned int u32x4 __attribute__((ext_vector_type(4)));

// dynamic LDS: weights only
#define OFF_W0   0        // 48*4*16*16B = 49152
#define OFF_W1   49152    // 64*4*16*16B = 65536
#define LDS_DYN  114688

__device__ __forceinline__ bf16x8 load_bf16x8(const __hip_bfloat16* p) {
    u32x4 u = *reinterpret_cast<const u32x4*>(p);
    return __builtin_bit_cast(bf16x8, u);
}
__device__ __forceinline__ f32x4 mfma16(bf16x8 a, bf16x8 b, f32x4 c) {
    return __builtin_amdgcn_mfma_f32_16x16x32_bf16(a, b, c, 0, 0, 0);
}
__device__ __forceinline__ float sigmoidf_(float x) {
    return 1.0f / (1.0f + __expf(-x));
}
__device__ __forceinline__ float tanhf_(float x) {
    return 1.0f - 2.0f / (__expf(2.0f * x) + 1.0f);
}

// ---------------------------------------------------------------------------
// Prep kernels (unchanged from round 2 — verified absmax 0.0)
// ---------------------------------------------------------------------------
template<int Ks>
__global__ __launch_bounds__(1024)
void pack_frag_kernel(const float* __restrict__ W, __hip_bfloat16* __restrict__ F)
{
    __shared__ float tile[32][33];
    const int k0 = blockIdx.x * 32;
    const int c0 = blockIdx.y * 32;
    const int tx = threadIdx.x & 31, ty = threadIdx.x >> 5;
    tile[ty][tx] = W[(size_t)(k0 + ty) * NCOL + (c0 + tx)];
    __syncthreads();
    const int cL  = threadIdx.x >> 5;
    const int kgw = (threadIdx.x >> 3) & 3;
    const int j   = threadIdx.x & 7;
    const int c   = c0 + cL;
    const int r   = (c & 1023) * 4 + (c >> 10);
    const int nb2 = r >> 4, cl = r & 15;
    const int ks  = k0 >> 5;
    const size_t chunk = ((size_t)(nb2 * Ks + ks) * 4 + kgw) * 16 + cl;
    F[chunk * 8 + j] = __float2bfloat16(tile[kgw * 8 + j][cL]);
}

__global__ void bias_reorder_kernel(const float* __restrict__ b0,
                                    const float* __restrict__ b1,
                                    float* __restrict__ b0r,
                                    float* __restrict__ b1r)
{
    int i = blockIdx.x * blockDim.x + threadIdx.x;
    if (i >= 2 * NCOL) return;
    const float* src = (i < NCOL) ? b0 : b1;
    float*       dst = (i < NCOL) ? b0r : b1r;
    int c = i & (NCOL - 1);
    dst[(c & 1023) * 4 + (c >> 10)] = src[c];
}

__global__ __launch_bounds__(256)
void xconv_kernel(const float* __restrict__ x, __hip_bfloat16* __restrict__ xb)
{
    const size_t i = ((size_t)blockIdx.x * 256 + threadIdx.x) * 8;
    f32x4 a = *(const f32x4*)(x + i);
    f32x4 b = *(const f32x4*)(x + i + 4);
    bf16x8 v;
    #pragma unroll
    for (int e = 0; e < 4; ++e) { v[e] = (__bf16)a[e]; v[e + 4] = (__bf16)b[e]; }
    *reinterpret_cast<u32x4*>((__hip_bfloat16*)xb + i) = __builtin_bit_cast(u32x4, v);
}

// ---------------------------------------------------------------------------
// Persistent kernel
// ---------------------------------------------------------------------------
template<bool XBF>
__global__ __launch_bounds__(1024)
void lstm_persistent(const float* __restrict__ x,
                     const __hip_bfloat16* __restrict__ xb,
                     const __hip_bfloat16* __restrict__ F0,
                     const __hip_bfloat16* __restrict__ F1,
                     const float* __restrict__ b0r,
                     const float* __restrict__ b1r,
                     const float* __restrict__ Wout,
                     const float* __restrict__ bout,
                     __hip_bfloat16* __restrict__ h0,   // 2 slots [128][1024]
                     __hip_bfloat16* __restrict__ h1,   // 2 slots
                     float* __restrict__ out,
                     int* __restrict__ bar)
{
    extern __shared__ char smem[];
    __hip_bfloat16* lW0 = (__hip_bfloat16*)(smem + OFF_W0);
    __hip_bfloat16* lW1 = (__hip_bfloat16*)(smem + OFF_W1);

    __shared__ float zacc[2][128][17];   // 17408 B
    __shared__ float cS[2][512];         // 4096 B
    __shared__ float biasS[2][16];       // 128 B

    const int tid  = threadIdx.x;
    const int lane = tid & 63;
    const int wv   = tid >> 6;           // 0..15
    const int kq   = wv & 3;             // k-group
    const int mq   = wv >> 2;            // m-group
    const int lm   = lane & 15;
    const int kg   = lane >> 4;
    const int nb   = blockIdx.x;
    const int HS   = BATCH * HID;
    const int row0 = mq * 32 + lm;
    const int row1 = row0 + 16;

    // ---- one-time init ----
    {
        const u32x4* s0 = (const u32x4*)(F0 + (size_t)nb * (KS0 * 64 * 8));
        u32x4*       d0 = (u32x4*)lW0;
        for (int i = tid; i < KS0 * 64; i += 1024) d0[i] = s0[i];
        const u32x4* s1 = (const u32x4*)(F1 + (size_t)nb * (KS1 * 64 * 8));
        u32x4*       d1 = (u32x4*)lW1;
        for (int i = tid; i < KS1 * 64; i += 1024) d1[i] = s1[i];
        if (tid < 32) biasS[tid >> 4][tid & 15] =
            ((tid < 16) ? b0r : b1r)[nb * 16 + (tid & 15)];
        cS[tid >> 9][tid & 511] = 0.f;
        for (int i = tid; i < 2 * 128 * 17; i += 1024) ((float*)zacc)[i] = 0.f;
    }
    __syncthreads();

    for (int p = 0; p <= SEQ; ++p) {
        const int sc = p & 1, sp = sc ^ 1;
        const __hip_bfloat16* h0prev = h0 + (size_t)sp * HS;  // h0(p-1)
        const __hip_bfloat16* h1prev = h1 + (size_t)sc * HS;  // h1(p-2)

        // ===== GEMM layer 0 (t = p) =====
        if (p < SEQ) {
            f32x4 acc0 = {0.f, 0.f, 0.f, 0.f}, acc1 = {0.f, 0.f, 0.f, 0.f};
            bf16x8 A0s[3], A1s[3], Bs[3];
            const size_t xoff = (size_t)p * INP;
            const __hip_bfloat16* hr0 = h0prev + (size_t)row0 * HID;
            const __hip_bfloat16* hr1 = h0prev + (size_t)row1 * HID;

            auto load0 = [&](int j, int pb) {
                const int ks = kq + 4 * j;
                Bs[pb] = *(const bf16x8*)(lW0 + (size_t)(((ks * 4 + kg) * 16 + lm) * 8));
                if (j < 4) {
                    const int k = ks * 32 + kg * 8;
                    if constexpr (XBF) {
                        A0s[pb] = load_bf16x8(xb + (size_t)row0 * (SEQ * INP) + xoff + k);
                        A1s[pb] = load_bf16x8(xb + (size_t)row1 * (SEQ * INP) + xoff + k);
                    } else {
                        const float* p0 = x + (size_t)row0 * (SEQ * INP) + xoff + k;
                        const float* p1 = x + (size_t)row1 * (SEQ * INP) + xoff + k;
                        f32x4 a = *(const f32x4*)p0, b = *(const f32x4*)(p0 + 4);
                        f32x4 c = *(const f32x4*)p1, d = *(const f32x4*)(p1 + 4);
                        bf16x8 v0, v1;
                        #pragma unroll
                        for (int e = 0; e < 4; ++e) {
                            v0[e] = (__bf16)a[e]; v0[e + 4] = (__bf16)b[e];
                            v1[e] = (__bf16)c[e]; v1[e + 4] = (__bf16)d[e];
                        }
                        A0s[pb] = v0; A1s[pb] = v1;
                    }
                } else {
                    const int k = ks * 32 + kg * 8 - INP;
                    A0s[pb] = load_bf16x8(hr0 + k);
                    A1s[pb] = load_bf16x8(hr1 + k);
                }
            };
            load0(0, 0); load0(1, 1);
            #pragma unroll
            for (int j = 0; j < 12; ++j) {
                if (j < 10) load0(j + 2, (j + 2) % 3);
                acc0 = mfma16(A0s[j % 3], Bs[j % 3], acc0);
                acc1 = mfma16(A1s[j % 3], Bs[j % 3], acc1);
            }
            #pragma unroll
            for (int r = 0; r < 4; ++r) {
                atomicAdd(&zacc[0][mq * 32 + kg * 4 + r][lm],      acc0[r]);
                atomicAdd(&zacc[0][mq * 32 + 16 + kg * 4 + r][lm], acc1[r]);
            }
        }

        // ===== GEMM layer 1 (t = p-1) =====
        if (p >= 1) {
            f32x4 acc0 = {0.f, 0.f, 0.f, 0.f}, acc1 = {0.f, 0.f, 0.f, 0.f};
            bf16x8 A0s[3], A1s[3], Bs[3];
            const __hip_bfloat16* g0 = h0prev + (size_t)row0 * HID;
            const __hip_bfloat16* g1 = h0prev + (size_t)row1 * HID;
            const __hip_bfloat16* q0 = h1prev + (size_t)row0 * HID;
            const __hip_bfloat16* q1 = h1prev + (size_t)row1 * HID;

            auto load1 = [&](int j, int pb) {
                const int ks = kq + 4 * j;
                Bs[pb] = *(const bf16x8*)(lW1 + (size_t)(((ks * 4 + kg) * 16 + lm) * 8));
                if (j < 8) {
                    const int k = ks * 32 + kg * 8;
                    A0s[pb] = load_bf16x8(g0 + k);
                    A1s[pb] = load_bf16x8(g1 + k);
                } else {
                    const int k = ks * 32 + kg * 8 - 1024;
                    A0s[pb] = load_bf16x8(q0 + k);
                    A1s[pb] = load_bf16x8(q1 + k);
                }
            };
            load1(0, 0); load1(1, 1);
            #pragma unroll
            for (int j = 0; j < 16; ++j) {
                if (j < 14) load1(j + 2, (j + 2) % 3);
                acc0 = mfma16(A0s[j % 3], Bs[j % 3], acc0);
                acc1 = mfma16(A1s[j % 3], Bs[j % 3], acc1);
            }
            #pragma unroll
            for (int r = 0; r < 4; ++r) {
                atomicAdd(&zacc[1][mq * 32 + kg * 4 + r][lm],      acc0[r]);
                atomicAdd(&zacc[1][mq * 32 + 16 + kg * 4 + r][lm], acc1[r]);
            }
        }
        __syncthreads();

        // ===== gates, both layers fused (1024 units) =====
        {
            const int L   = tid >> 9;
            const int idx = tid & 511;
            const int bl  = idx >> 2;
            const int u   = idx & 3;
            const bool act = L ? (p >= 1) : (p < SEQ);
            if (act) {
                float* zb = &zacc[L][bl][4 * u];
                const float zf = zb[0] + biasS[L][4 * u + 0];
                const float zi = zb[1] + biasS[L][4 * u + 1];
                const float zo = zb[2] + biasS[L][4 * u + 2];
                const float zg = zb[3] + biasS[L][4 * u + 3];
                zb[0] = 0.f; zb[1] = 0.f; zb[2] = 0.f; zb[3] = 0.f;  // self-clear
                const float cold = cS[L][idx];
                const float cn = sigmoidf_(zf) * cold + sigmoidf_(zi) * tanhf_(zg);
                const float hn = sigmoidf_(zo) * tanhf_(cn);
                cS[L][idx] = cn;
                __hip_bfloat16* hw = L ? (h1 + (size_t)sp * HS) : (h0 + (size_t)sc * HS);
                hw[(size_t)bl * HID + nb * 4 + u] = __float2bfloat16(hn);
            }
        }

        // ===== grid barrier =====
        __builtin_amdgcn_fence(__ATOMIC_RELEASE, "workgroup");  // drain my stores
        __syncthreads();                                        // whole block's stores in L2
        if (tid == 0) {
            __builtin_amdgcn_fence(__ATOMIC_RELEASE, "agent");  // wbl2 -> L3
            __hip_atomic_fetch_add(bar, 1, __ATOMIC_RELAXED, __HIP_MEMORY_SCOPE_AGENT);
            const int tgt = NB * (p + 1);
            while (__hip_atomic_load(bar, __ATOMIC_RELAXED, __HIP_MEMORY_SCOPE_AGENT) < tgt)
                __builtin_amdgcn_s_sleep(2);
            __builtin_amdgcn_fence(__ATOMIC_ACQUIRE, "agent");  // inv L1+L2
        }
        __syncthreads();
    }

    // ---- head: out[b] = sigmoid(h1(511) . Wout + bout); h1(511) in slot 1
    if (nb == 0 && tid < BATCH) {
        const __hip_bfloat16* hr = h1 + (size_t)1 * HS + (size_t)tid * HID;
        float acc = 0.f;
        for (int k2 = 0; k2 < HID; k2 += 8) {
            bf16x8 v = load_bf16x8(hr + k2);
            #pragma unroll
            for (int j = 0; j < 8; ++j)
                acc += (float)v[j] * Wout[k2 + j];
        }
        out[tid] = 1.f / (1.f + __expf(-(acc + bout[0])));
    }
}

// ---------------------------------------------------------------------------
extern "C" void kernel_launch(void* const* d_in, const int* in_sizes, int n_in,
                              void* d_out, int out_size, void* d_ws, size_t ws_size,
                              hipStream_t stream)
{
    const float* x    = (const float*)d_in[0];   // [128][512][512]
    const float* W0   = (const float*)d_in[1];   // [1536][4096]
    const float* b0   = (const float*)d_in[2];   // [4096]
    const float* W1   = (const float*)d_in[3];   // [2048][4096]
    const float* b1   = (const float*)d_in[4];   // [4096]
    const float* Wout = (const float*)d_in[5];   // [1024]
    const float* bout = (const float*)d_in[6];   // [1]
    float* out = (float*)d_out;

    char* ws = (char*)d_ws;
    const size_t OFF_F0  = 0;            // 12,582,912
    const size_t OFF_F1  = 12582912;     // 16,777,216
    const size_t OFF_B0R = 29360128;     // 16,384
    const size_t OFF_B1R = 29376512;     // 16,384
    const size_t OFF_H0  = 29392896;     // 524,288
    const size_t OFF_H1  = 29917184;     // 524,288
    const size_t OFF_BAR = 30441472;     // 256
    const size_t OFF_XB  = 30441728;     // 67,108,864
    const size_t NEED_XBF = OFF_XB + (size_t)BATCH * SEQ * INP * 2;

    __hip_bfloat16* F0 = (__hip_bfloat16*)(ws + OFF_F0);
    __hip_bfloat16* F1 = (__hip_bfloat16*)(ws + OFF_F1);
    float* b0r = (float*)(ws + OFF_B0R);
    float* b1r = (float*)(ws + OFF_B1R);
    __hip_bfloat16* h0 = (__hip_bfloat16*)(ws + OFF_H0);
    __hip_bfloat16* h1 = (__hip_bfloat16*)(ws + OFF_H1);
    int* bar = (int*)(ws + OFF_BAR);
    __hip_bfloat16* xbp = (__hip_bfloat16*)(ws + OFF_XB);

    const bool xbf = (ws_size >= NEED_XBF);

    // zero h slots + barrier counter (every call: harness doesn't re-poison)
    hipMemsetAsync(ws + OFF_H0, 0, OFF_BAR + 256 - OFF_H0, stream);

    pack_frag_kernel<KS0><<<dim3(48, 128), 1024, 0, stream>>>(W0, F0);
    pack_frag_kernel<KS1><<<dim3(64, 128), 1024, 0, stream>>>(W1, F1);
    bias_reorder_kernel<<<32, 256, 0, stream>>>(b0, b1, b0r, b1r);
    if (xbf)
        xconv_kernel<<<(BATCH * SEQ * INP) / (256 * 8), 256, 0, stream>>>(x, xbp);

    hipFuncSetAttribute((const void*)lstm_persistent<true>,
                        hipFuncAttributeMaxDynamicSharedMemorySize, LDS_DYN);
    hipFuncSetAttribute((const void*)lstm_persistent<false>,
                        hipFuncAttributeMaxDynamicSharedMemorySize, LDS_DYN);

    void* args[] = {(void*)&x, (void*)&xbp, (void*)&F0, (void*)&F1,
                    (void*)&b0r, (void*)&b1r, (void*)&Wout, (void*)&bout,
                    (void*)&h0, (void*)&h1, (void*)&out, (void*)&bar};
    if (xbf)
        hipLaunchCooperativeKernel((void*)lstm_persistent<true>, dim3(NB),
                                   dim3(1024), args, LDS_DYN, stream);
    else
        hipLaunchCooperativeKernel((void*)lstm_persistent<false>, dim3(NB),
                                   dim3(1024), args, LDS_DYN, stream);
}

// Round 4
// 27000.912 us; speedup vs baseline: 1.6782x; 1.0685x over previous
//
#include <hip/hip_runtime.h>
#include <hip/hip_bf16.h>
#include <cstdint>
#include <cstddef>

// SimpleXLSTM persistent-kernel round 4.
// 2-layer LSTM (B=128, T=512, IN=512, H=1024) + sigmoid head.
// 256 blocks x 1024 threads. Weights in LDS. NO cache-maintenance barrier:
// h state read/written via agent-scope relaxed atomics (L1/L2 bypass to L3),
// x/weights stay normally cached. Hierarchical relaxed-counter grid barrier.
// 4-deep A-fragment prefetch ring.

#define BATCH 128
#define SEQ   512
#define INP   512
#define HID   1024
#define NCOL  4096
#define NB    256
#define KS0   48
#define KS1   64

typedef __bf16 bf16x8 __attribute__((ext_vector_type(8)));
typedef float  f32x4  __attribute__((ext_vector_type(4)));
typedef unsigned int u32x4 __attribute__((ext_vector_type(4)));
typedef unsigned long long u64;
typedef u64 u64x2 __attribute__((ext_vector_type(2)));

#define OFF_W0   0        // 49152
#define OFF_W1   49152    // 65536
#define LDS_DYN  114688

__device__ __forceinline__ bf16x8 load_bf16x8(const __hip_bfloat16* p) {
    u32x4 u = *reinterpret_cast<const u32x4*>(p);
    return __builtin_bit_cast(bf16x8, u);
}
// agent-scope bypass load of one 16B fragment as 2x8B atomics
__device__ __forceinline__ bf16x8 aload_bf16x8(const __hip_bfloat16* p) {
    u64x2 q;
    q[0] = __hip_atomic_load((const u64*)p,       __ATOMIC_RELAXED, __HIP_MEMORY_SCOPE_AGENT);
    q[1] = __hip_atomic_load((const u64*)(p + 4), __ATOMIC_RELAXED, __HIP_MEMORY_SCOPE_AGENT);
    return __builtin_bit_cast(bf16x8, q);
}
__device__ __forceinline__ f32x4 mfma16(bf16x8 a, bf16x8 b, f32x4 c) {
    return __builtin_amdgcn_mfma_f32_16x16x32_bf16(a, b, c, 0, 0, 0);
}
__device__ __forceinline__ float sigmoidf_(float x) {
    return 1.0f / (1.0f + __expf(-x));
}
__device__ __forceinline__ float tanhf_(float x) {
    return 1.0f - 2.0f / (__expf(2.0f * x) + 1.0f);
}

// ---------------------------------------------------------------------------
// Prep kernels (verified rounds 2-3)
// ---------------------------------------------------------------------------
template<int Ks>
__global__ __launch_bounds__(1024)
void pack_frag_kernel(const float* __restrict__ W, __hip_bfloat16* __restrict__ F)
{
    __shared__ float tile[32][33];
    const int k0 = blockIdx.x * 32;
    const int c0 = blockIdx.y * 32;
    const int tx = threadIdx.x & 31, ty = threadIdx.x >> 5;
    tile[ty][tx] = W[(size_t)(k0 + ty) * NCOL + (c0 + tx)];
    __syncthreads();
    const int cL  = threadIdx.x >> 5;
    const int kgw = (threadIdx.x >> 3) & 3;
    const int j   = threadIdx.x & 7;
    const int c   = c0 + cL;
    const int r   = (c & 1023) * 4 + (c >> 10);
    const int nb2 = r >> 4, cl = r & 15;
    const int ks  = k0 >> 5;
    const size_t chunk = ((size_t)(nb2 * Ks + ks) * 4 + kgw) * 16 + cl;
    F[chunk * 8 + j] = __float2bfloat16(tile[kgw * 8 + j][cL]);
}

__global__ void bias_reorder_kernel(const float* __restrict__ b0,
                                    const float* __restrict__ b1,
                                    float* __restrict__ b0r,
                                    float* __restrict__ b1r)
{
    int i = blockIdx.x * blockDim.x + threadIdx.x;
    if (i >= 2 * NCOL) return;
    const float* src = (i < NCOL) ? b0 : b1;
    float*       dst = (i < NCOL) ? b0r : b1r;
    int c = i & (NCOL - 1);
    dst[(c & 1023) * 4 + (c >> 10)] = src[c];
}

__global__ __launch_bounds__(256)
void xconv_kernel(const float* __restrict__ x, __hip_bfloat16* __restrict__ xb)
{
    const size_t i = ((size_t)blockIdx.x * 256 + threadIdx.x) * 8;
    f32x4 a = *(const f32x4*)(x + i);
    f32x4 b = *(const f32x4*)(x + i + 4);
    bf16x8 v;
    #pragma unroll
    for (int e = 0; e < 4; ++e) { v[e] = (__bf16)a[e]; v[e + 4] = (__bf16)b[e]; }
    *reinterpret_cast<u32x4*>((__hip_bfloat16*)xb + i) = __builtin_bit_cast(u32x4, v);
}

// ---------------------------------------------------------------------------
template<bool XBF>
__global__ __launch_bounds__(1024)
void lstm_persistent(const float* __restrict__ x,
                     const __hip_bfloat16* __restrict__ xb,
                     const __hip_bfloat16* __restrict__ F0,
                     const __hip_bfloat16* __restrict__ F1,
                     const float* __restrict__ b0r,
                     const float* __restrict__ b1r,
                     const float* __restrict__ Wout,
                     const float* __restrict__ bout,
                     __hip_bfloat16* __restrict__ h0,
                     __hip_bfloat16* __restrict__ h1,
                     float* __restrict__ out,
                     int* __restrict__ bar)
{
    extern __shared__ char smem[];
    __hip_bfloat16* lW0 = (__hip_bfloat16*)(smem + OFF_W0);
    __hip_bfloat16* lW1 = (__hip_bfloat16*)(smem + OFF_W1);

    __shared__ float zacc[2][128][17];                 // 17408 B
    __shared__ float cS[2][512];                        // 4096 B
    __shared__ float biasS[2][16];                      // 128 B
    __shared__ __hip_bfloat16 hstage[2][128][4];        // 2048 B

    const int tid  = threadIdx.x;
    const int lane = tid & 63;
    const int wv   = tid >> 6;
    const int kq   = wv & 3;
    const int mq   = wv >> 2;
    const int lm   = lane & 15;
    const int kg   = lane >> 4;
    const int nb   = blockIdx.x;
    const int HS   = BATCH * HID;
    const int row0 = mq * 32 + lm;
    const int row1 = row0 + 16;

    // ---- one-time init ----
    {
        const u32x4* s0 = (const u32x4*)(F0 + (size_t)nb * (KS0 * 64 * 8));
        u32x4*       d0 = (u32x4*)lW0;
        for (int i = tid; i < KS0 * 64; i += 1024) d0[i] = s0[i];
        const u32x4* s1 = (const u32x4*)(F1 + (size_t)nb * (KS1 * 64 * 8));
        u32x4*       d1 = (u32x4*)lW1;
        for (int i = tid; i < KS1 * 64; i += 1024) d1[i] = s1[i];
        if (tid < 32) biasS[tid >> 4][tid & 15] =
            ((tid < 16) ? b0r : b1r)[nb * 16 + (tid & 15)];
        cS[tid >> 9][tid & 511] = 0.f;
        for (int i = tid; i < 2 * 128 * 17; i += 1024) ((float*)zacc)[i] = 0.f;
    }
    __syncthreads();

    for (int p = 0; p <= SEQ; ++p) {
        const int sc = p & 1, sp = sc ^ 1;
        const __hip_bfloat16* h0prev = h0 + (size_t)sp * HS;  // h0(p-1)
        const __hip_bfloat16* h1prev = h1 + (size_t)sc * HS;  // h1(p-2)

        // ===== GEMM layer 0 (t = p): A = [x(t), h0prev] =====
        if (p < SEQ) {
            f32x4 acc0 = {0.f, 0.f, 0.f, 0.f}, acc1 = {0.f, 0.f, 0.f, 0.f};
            bf16x8 A0s[4], A1s[4], Bs[4];
            const size_t xoff = (size_t)p * INP;
            const __hip_bfloat16* hr0 = h0prev + (size_t)row0 * HID;
            const __hip_bfloat16* hr1 = h0prev + (size_t)row1 * HID;

            auto load0 = [&](int j, int s) {
                const int ks = kq + 4 * j;
                Bs[s] = *(const bf16x8*)(lW0 + (size_t)(((ks * 4 + kg) * 16 + lm) * 8));
                if (j < 4) {
                    const int k = ks * 32 + kg * 8;
                    if constexpr (XBF) {
                        A0s[s] = load_bf16x8(xb + (size_t)row0 * (SEQ * INP) + xoff + k);
                        A1s[s] = load_bf16x8(xb + (size_t)row1 * (SEQ * INP) + xoff + k);
                    } else {
                        const float* p0 = x + (size_t)row0 * (SEQ * INP) + xoff + k;
                        const float* p1 = x + (size_t)row1 * (SEQ * INP) + xoff + k;
                        f32x4 a = *(const f32x4*)p0, b = *(const f32x4*)(p0 + 4);
                        f32x4 c = *(const f32x4*)p1, d = *(const f32x4*)(p1 + 4);
                        bf16x8 v0, v1;
                        #pragma unroll
                        for (int e = 0; e < 4; ++e) {
                            v0[e] = (__bf16)a[e]; v0[e + 4] = (__bf16)b[e];
                            v1[e] = (__bf16)c[e]; v1[e + 4] = (__bf16)d[e];
                        }
                        A0s[s] = v0; A1s[s] = v1;
                    }
                } else {
                    const int k = ks * 32 + kg * 8 - INP;
                    A0s[s] = aload_bf16x8(hr0 + k);
                    A1s[s] = aload_bf16x8(hr1 + k);
                }
            };
            #pragma unroll
            for (int j = 0; j < 4; ++j) load0(j, j);
            #pragma unroll
            for (int j = 0; j < 12; ++j) {
                acc0 = mfma16(A0s[j & 3], Bs[j & 3], acc0);
                acc1 = mfma16(A1s[j & 3], Bs[j & 3], acc1);
                if (j < 8) load0(j + 4, j & 3);
            }
            #pragma unroll
            for (int r = 0; r < 4; ++r) {
                atomicAdd(&zacc[0][mq * 32 + kg * 4 + r][lm],      acc0[r]);
                atomicAdd(&zacc[0][mq * 32 + 16 + kg * 4 + r][lm], acc1[r]);
            }
        }

        // ===== GEMM layer 1 (t = p-1): A = [h0prev, h1prev] =====
        if (p >= 1) {
            f32x4 acc0 = {0.f, 0.f, 0.f, 0.f}, acc1 = {0.f, 0.f, 0.f, 0.f};
            bf16x8 A0s[4], A1s[4], Bs[4];
            const __hip_bfloat16* g0 = h0prev + (size_t)row0 * HID;
            const __hip_bfloat16* g1 = h0prev + (size_t)row1 * HID;
            const __hip_bfloat16* q0 = h1prev + (size_t)row0 * HID;
            const __hip_bfloat16* q1 = h1prev + (size_t)row1 * HID;

            auto load1 = [&](int j, int s) {
                const int ks = kq + 4 * j;
                Bs[s] = *(const bf16x8*)(lW1 + (size_t)(((ks * 4 + kg) * 16 + lm) * 8));
                if (j < 8) {
                    const int k = ks * 32 + kg * 8;
                    A0s[s] = aload_bf16x8(g0 + k);
                    A1s[s] = aload_bf16x8(g1 + k);
                } else {
                    const int k = ks * 32 + kg * 8 - 1024;
                    A0s[s] = aload_bf16x8(q0 + k);
                    A1s[s] = aload_bf16x8(q1 + k);
                }
            };
            #pragma unroll
            for (int j = 0; j < 4; ++j) load1(j, j);
            #pragma unroll
            for (int j = 0; j < 16; ++j) {
                acc0 = mfma16(A0s[j & 3], Bs[j & 3], acc0);
                acc1 = mfma16(A1s[j & 3], Bs[j & 3], acc1);
                if (j < 12) load1(j + 4, j & 3);
            }
            #pragma unroll
            for (int r = 0; r < 4; ++r) {
                atomicAdd(&zacc[1][mq * 32 + kg * 4 + r][lm],      acc0[r]);
                atomicAdd(&zacc[1][mq * 32 + 16 + kg * 4 + r][lm], acc1[r]);
            }
        }
        __syncthreads();

        // ===== gates -> hstage (LDS) =====
        {
            const int L   = tid >> 9;
            const int idx = tid & 511;
            const int bl  = idx >> 2;
            const int u   = idx & 3;
            const bool act = L ? (p >= 1) : (p < SEQ);
            if (act) {
                float* zb = &zacc[L][bl][4 * u];
                const float zf = zb[0] + biasS[L][4 * u + 0];
                const float zi = zb[1] + biasS[L][4 * u + 1];
                const float zo = zb[2] + biasS[L][4 * u + 2];
                const float zg = zb[3] + biasS[L][4 * u + 3];
                zb[0] = 0.f; zb[1] = 0.f; zb[2] = 0.f; zb[3] = 0.f;
                const float cold = cS[L][idx];
                const float cn = sigmoidf_(zf) * cold + sigmoidf_(zi) * tanhf_(zg);
                const float hn = sigmoidf_(zo) * tanhf_(cn);
                cS[L][idx] = cn;
                hstage[L][bl][u] = __float2bfloat16(hn);
            }
        }
        __syncthreads();

        // ===== coalesced 8B bypass stores of h =====
        if (tid < 256) {
            const int L  = tid >> 7;
            const int bl = tid & 127;
            const bool act = L ? (p >= 1) : (p < SEQ);
            if (act) {
                __hip_bfloat16* hw = L ? (h1 + (size_t)sp * HS) : (h0 + (size_t)sc * HS);
                const u64 v = *(const u64*)&hstage[L][bl][0];
                __hip_atomic_store((u64*)(hw + (size_t)bl * HID + nb * 4), v,
                                   __ATOMIC_RELAXED, __HIP_MEMORY_SCOPE_AGENT);
            }
        }
        __syncthreads();   // drains every wave's vmcnt -> stores acked at L3

        // ===== hierarchical grid barrier (no cache maintenance) =====
        if (tid == 0) {
            asm volatile("s_waitcnt vmcnt(0)" ::: "memory");
            int* grp = bar + 32 * (1 + (nb >> 5));
            __hip_atomic_fetch_add(grp, 1, __ATOMIC_RELAXED, __HIP_MEMORY_SCOPE_AGENT);
            if ((nb & 31) == 0) {
                const int gt = 32 * (p + 1);
                while (__hip_atomic_load(grp, __ATOMIC_RELAXED, __HIP_MEMORY_SCOPE_AGENT) < gt)
                    __builtin_amdgcn_s_sleep(1);
                __hip_atomic_fetch_add(bar, 1, __ATOMIC_RELAXED, __HIP_MEMORY_SCOPE_AGENT);
            }
            const int rt = 8 * (p + 1);
            while (__hip_atomic_load(bar, __ATOMIC_RELAXED, __HIP_MEMORY_SCOPE_AGENT) < rt)
                __builtin_amdgcn_s_sleep(1);
            asm volatile("" ::: "memory");
        }
        __syncthreads();
    }

    // ---- head: out[b] = sigmoid(h1(511) . Wout + bout); slot 1 ----
    if (nb == 0 && tid < BATCH) {
        const __hip_bfloat16* hr = h1 + (size_t)1 * HS + (size_t)tid * HID;
        float acc = 0.f;
        for (int k2 = 0; k2 < HID; k2 += 8) {
            bf16x8 v = aload_bf16x8(hr + k2);
            #pragma unroll
            for (int j = 0; j < 8; ++j)
                acc += (float)v[j] * Wout[k2 + j];
        }
        out[tid] = 1.f / (1.f + __expf(-(acc + bout[0])));
    }
}

// ---------------------------------------------------------------------------
extern "C" void kernel_launch(void* const* d_in, const int* in_sizes, int n_in,
                              void* d_out, int out_size, void* d_ws, size_t ws_size,
                              hipStream_t stream)
{
    const float* x    = (const float*)d_in[0];
    const float* W0   = (const float*)d_in[1];
    const float* b0   = (const float*)d_in[2];
    const float* W1   = (const float*)d_in[3];
    const float* b1   = (const float*)d_in[4];
    const float* Wout = (const float*)d_in[5];
    const float* bout = (const float*)d_in[6];
    float* out = (float*)d_out;

    char* ws = (char*)d_ws;
    const size_t OFF_F0  = 0;            // 12,582,912
    const size_t OFF_F1  = 12582912;     // 16,777,216
    const size_t OFF_B0R = 29360128;     // 16,384
    const size_t OFF_B1R = 29376512;     // 16,384
    const size_t OFF_H0  = 29392896;     // 524,288
    const size_t OFF_H1  = 29917184;     // 524,288
    const size_t OFF_BAR = 30441472;     // 4,096
    const size_t OFF_XB  = 30445568;     // 67,108,864
    const size_t NEED_XBF = OFF_XB + (size_t)BATCH * SEQ * INP * 2;

    __hip_bfloat16* F0 = (__hip_bfloat16*)(ws + OFF_F0);
    __hip_bfloat16* F1 = (__hip_bfloat16*)(ws + OFF_F1);
    float* b0r = (float*)(ws + OFF_B0R);
    float* b1r = (float*)(ws + OFF_B1R);
    __hip_bfloat16* h0 = (__hip_bfloat16*)(ws + OFF_H0);
    __hip_bfloat16* h1 = (__hip_bfloat16*)(ws + OFF_H1);
    int* bar = (int*)(ws + OFF_BAR);
    __hip_bfloat16* xbp = (__hip_bfloat16*)(ws + OFF_XB);

    const bool xbf = (ws_size >= NEED_XBF);

    // zero h slots + barrier counters every call (graph replays included)
    hipMemsetAsync(ws + OFF_H0, 0, OFF_BAR + 4096 - OFF_H0, stream);

    pack_frag_kernel<KS0><<<dim3(48, 128), 1024, 0, stream>>>(W0, F0);
    pack_frag_kernel<KS1><<<dim3(64, 128), 1024, 0, stream>>>(W1, F1);
    bias_reorder_kernel<<<32, 256, 0, stream>>>(b0, b1, b0r, b1r);
    if (xbf)
        xconv_kernel<<<(BATCH * SEQ * INP) / (256 * 8), 256, 0, stream>>>(x, xbp);

    hipFuncSetAttribute((const void*)lstm_persistent<true>,
                        hipFuncAttributeMaxDynamicSharedMemorySize, LDS_DYN);
    hipFuncSetAttribute((const void*)lstm_persistent<false>,
                        hipFuncAttributeMaxDynamicSharedMemorySize, LDS_DYN);

    void* args[] = {(void*)&x, (void*)&xbp, (void*)&F0, (void*)&F1,
                    (void*)&b0r, (void*)&b1r, (void*)&Wout, (void*)&bout,
                    (void*)&h0, (void*)&h1, (void*)&out, (void*)&bar};
    if (xbf)
        hipLaunchCooperativeKernel((void*)lstm_persistent<true>, dim3(NB),
                                   dim3(1024), args, LDS_DYN, stream);
    else
        hipLaunchCooperativeKernel((void*)lstm_persistent<false>, dim3(NB),
                                   dim3(1024), args, LDS_DYN, stream);
}

// Round 5
// 20221.857 us; speedup vs baseline: 2.2408x; 1.3352x over previous
//
#include <hip/hip_runtime.h>
#include <hip/hip_bf16.h>
#include <cstdint>
#include <cstddef>

// SimpleXLSTM persistent-kernel round 5.
// Key change vs round 4: h state is communicated through 64-generation
// "virgin address" rings. Writers: 8B agent-scope bypass stores (to L3).
// Readers: PLAIN CACHED loads (L2 dedup across the 32 blocks of an XCD) --
// safe because a ring address is never re-read within 64 phases and every
// block runs fence(acquire,agent) every 32 phases, bounding cache lifetime.
// Barrier polling stays on bypass atomics (cached polls would deadlock).

#define BATCH 128
#define SEQ   512
#define INP   512
#define HID   1024
#define NCOL  4096
#define NB    256
#define KS0   48
#define KS1   64

typedef __bf16 bf16x8 __attribute__((ext_vector_type(8)));
typedef float  f32x4  __attribute__((ext_vector_type(4)));
typedef unsigned int u32x4 __attribute__((ext_vector_type(4)));
typedef unsigned long long u64;
typedef u64 u64x2 __attribute__((ext_vector_type(2)));

#define OFF_W0   0        // 49152
#define OFF_W1   49152    // 65536
#define LDS_DYN  114688

__device__ __forceinline__ bf16x8 load_bf16x8(const __hip_bfloat16* p) {
    u32x4 u = *reinterpret_cast<const u32x4*>(p);
    return __builtin_bit_cast(bf16x8, u);
}
__device__ __forceinline__ bf16x8 aload_bf16x8(const __hip_bfloat16* p) {
    u64x2 q;
    q[0] = __hip_atomic_load((const u64*)p,       __ATOMIC_RELAXED, __HIP_MEMORY_SCOPE_AGENT);
    q[1] = __hip_atomic_load((const u64*)(p + 4), __ATOMIC_RELAXED, __HIP_MEMORY_SCOPE_AGENT);
    return __builtin_bit_cast(bf16x8, q);
}
__device__ __forceinline__ f32x4 mfma16(bf16x8 a, bf16x8 b, f32x4 c) {
    return __builtin_amdgcn_mfma_f32_16x16x32_bf16(a, b, c, 0, 0, 0);
}
__device__ __forceinline__ float sigmoidf_(float x) {
    return 1.0f / (1.0f + __expf(-x));
}
__device__ __forceinline__ float tanhf_(float x) {
    return 1.0f - 2.0f / (__expf(2.0f * x) + 1.0f);
}

// ---------------------------------------------------------------------------
// Prep kernels (verified rounds 2-4)
// ---------------------------------------------------------------------------
template<int Ks>
__global__ __launch_bounds__(1024)
void pack_frag_kernel(const float* __restrict__ W, __hip_bfloat16* __restrict__ F)
{
    __shared__ float tile[32][33];
    const int k0 = blockIdx.x * 32;
    const int c0 = blockIdx.y * 32;
    const int tx = threadIdx.x & 31, ty = threadIdx.x >> 5;
    tile[ty][tx] = W[(size_t)(k0 + ty) * NCOL + (c0 + tx)];
    __syncthreads();
    const int cL  = threadIdx.x >> 5;
    const int kgw = (threadIdx.x >> 3) & 3;
    const int j   = threadIdx.x & 7;
    const int c   = c0 + cL;
    const int r   = (c & 1023) * 4 + (c >> 10);
    const int nb2 = r >> 4, cl = r & 15;
    const int ks  = k0 >> 5;
    const size_t chunk = ((size_t)(nb2 * Ks + ks) * 4 + kgw) * 16 + cl;
    F[chunk * 8 + j] = __float2bfloat16(tile[kgw * 8 + j][cL]);
}

__global__ void bias_reorder_kernel(const float* __restrict__ b0,
                                    const float* __restrict__ b1,
                                    float* __restrict__ b0r,
                                    float* __restrict__ b1r)
{
    int i = blockIdx.x * blockDim.x + threadIdx.x;
    if (i >= 2 * NCOL) return;
    const float* src = (i < NCOL) ? b0 : b1;
    float*       dst = (i < NCOL) ? b0r : b1r;
    int c = i & (NCOL - 1);
    dst[(c & 1023) * 4 + (c >> 10)] = src[c];
}

__global__ __launch_bounds__(256)
void xconv_kernel(const float* __restrict__ x, __hip_bfloat16* __restrict__ xb)
{
    const size_t i = ((size_t)blockIdx.x * 256 + threadIdx.x) * 8;
    f32x4 a = *(const f32x4*)(x + i);
    f32x4 b = *(const f32x4*)(x + i + 4);
    bf16x8 v;
    #pragma unroll
    for (int e = 0; e < 4; ++e) { v[e] = (__bf16)a[e]; v[e + 4] = (__bf16)b[e]; }
    *reinterpret_cast<u32x4*>((__hip_bfloat16*)xb + i) = __builtin_bit_cast(u32x4, v);
}

// ---------------------------------------------------------------------------
// Persistent kernel.  FRESH: 64-slot rings + cached h loads + periodic fence.
// !FRESH (small-ws fallback): 2-slot rings + bypass h loads (round-4 path).
// ---------------------------------------------------------------------------
template<bool XBF, bool FRESH>
__global__ __launch_bounds__(1024)
void lstm_persistent(const float* __restrict__ x,
                     const __hip_bfloat16* __restrict__ xb,
                     const __hip_bfloat16* __restrict__ F0,
                     const __hip_bfloat16* __restrict__ F1,
                     const float* __restrict__ b0r,
                     const float* __restrict__ b1r,
                     const float* __restrict__ Wout,
                     const float* __restrict__ bout,
                     __hip_bfloat16* __restrict__ h0r,
                     __hip_bfloat16* __restrict__ h1r,
                     float* __restrict__ out,
                     int* __restrict__ bar)
{
    constexpr int RMASK = FRESH ? 63 : 1;

    extern __shared__ char smem[];
    __hip_bfloat16* lW0 = (__hip_bfloat16*)(smem + OFF_W0);
    __hip_bfloat16* lW1 = (__hip_bfloat16*)(smem + OFF_W1);

    __shared__ float zacc[2][128][17];
    __shared__ float cS[2][512];
    __shared__ float biasS[2][16];
    __shared__ __hip_bfloat16 hstage[2][128][4];

    const int tid  = threadIdx.x;
    const int lane = tid & 63;
    const int wv   = tid >> 6;
    const int kq   = wv & 3;
    const int mq   = wv >> 2;
    const int lm   = lane & 15;
    const int kg   = lane >> 4;
    const int nb   = blockIdx.x;
    const int HS   = BATCH * HID;
    const int row0 = mq * 32 + lm;
    const int row1 = row0 + 16;

    // ---- one-time init ----
    {
        const u32x4* s0 = (const u32x4*)(F0 + (size_t)nb * (KS0 * 64 * 8));
        u32x4*       d0 = (u32x4*)lW0;
        for (int i = tid; i < KS0 * 64; i += 1024) d0[i] = s0[i];
        const u32x4* s1 = (const u32x4*)(F1 + (size_t)nb * (KS1 * 64 * 8));
        u32x4*       d1 = (u32x4*)lW1;
        for (int i = tid; i < KS1 * 64; i += 1024) d1[i] = s1[i];
        if (tid < 32) biasS[tid >> 4][tid & 15] =
            ((tid < 16) ? b0r : b1r)[nb * 16 + (tid & 15)];
        cS[tid >> 9][tid & 511] = 0.f;
        for (int i = tid; i < 2 * 128 * 17; i += 1024) ((float*)zacc)[i] = 0.f;
    }
    __syncthreads();

    for (int p = 0; p <= SEQ; ++p) {
        // ring slots: h0(t) at slot t&RMASK, h1(t) at slot t&RMASK
        const __hip_bfloat16* h0prev = h0r + (size_t)((p + RMASK)     & RMASK) * HS; // h0(p-1)
        const __hip_bfloat16* h1prev = h1r + (size_t)((p + RMASK - 1) & RMASK) * HS; // h1(p-2)
        __hip_bfloat16*       h0w    = h0r + (size_t)( p              & RMASK) * HS; // h0(p)
        __hip_bfloat16*       h1w    = h1r + (size_t)((p + RMASK)     & RMASK) * HS; // h1(p-1)

        // ===== GEMM layer 0 (t = p): A = [x(t), h0prev] =====
        if (p < SEQ) {
            f32x4 acc0 = {0.f, 0.f, 0.f, 0.f}, acc1 = {0.f, 0.f, 0.f, 0.f};
            bf16x8 A0s[4], A1s[4], Bs[4];
            const size_t xoff = (size_t)p * INP;
            const __hip_bfloat16* hr0 = h0prev + (size_t)row0 * HID;
            const __hip_bfloat16* hr1 = h0prev + (size_t)row1 * HID;

            auto load0 = [&](int j, int s) {
                const int ks = kq + 4 * j;
                Bs[s] = *(const bf16x8*)(lW0 + (size_t)(((ks * 4 + kg) * 16 + lm) * 8));
                if (j < 4) {
                    const int k = ks * 32 + kg * 8;
                    if constexpr (XBF) {
                        A0s[s] = load_bf16x8(xb + (size_t)row0 * (SEQ * INP) + xoff + k);
                        A1s[s] = load_bf16x8(xb + (size_t)row1 * (SEQ * INP) + xoff + k);
                    } else {
                        const float* p0 = x + (size_t)row0 * (SEQ * INP) + xoff + k;
                        const float* p1 = x + (size_t)row1 * (SEQ * INP) + xoff + k;
                        f32x4 a = *(const f32x4*)p0, b = *(const f32x4*)(p0 + 4);
                        f32x4 c = *(const f32x4*)p1, d = *(const f32x4*)(p1 + 4);
                        bf16x8 v0, v1;
                        #pragma unroll
                        for (int e = 0; e < 4; ++e) {
                            v0[e] = (__bf16)a[e]; v0[e + 4] = (__bf16)b[e];
                            v1[e] = (__bf16)c[e]; v1[e + 4] = (__bf16)d[e];
                        }
                        A0s[s] = v0; A1s[s] = v1;
                    }
                } else {
                    const int k = ks * 32 + kg * 8 - INP;
                    if constexpr (FRESH) {
                        A0s[s] = load_bf16x8(hr0 + k);
                        A1s[s] = load_bf16x8(hr1 + k);
                    } else {
                        A0s[s] = aload_bf16x8(hr0 + k);
                        A1s[s] = aload_bf16x8(hr1 + k);
                    }
                }
            };
            #pragma unroll
            for (int j = 0; j < 4; ++j) load0(j, j);
            #pragma unroll
            for (int j = 0; j < 12; ++j) {
                acc0 = mfma16(A0s[j & 3], Bs[j & 3], acc0);
                acc1 = mfma16(A1s[j & 3], Bs[j & 3], acc1);
                if (j < 8) load0(j + 4, j & 3);
            }
            #pragma unroll
            for (int r = 0; r < 4; ++r) {
                atomicAdd(&zacc[0][mq * 32 + kg * 4 + r][lm],      acc0[r]);
                atomicAdd(&zacc[0][mq * 32 + 16 + kg * 4 + r][lm], acc1[r]);
            }
        }

        // ===== GEMM layer 1 (t = p-1): A = [h0prev, h1prev] =====
        if (p >= 1) {
            f32x4 acc0 = {0.f, 0.f, 0.f, 0.f}, acc1 = {0.f, 0.f, 0.f, 0.f};
            bf16x8 A0s[4], A1s[4], Bs[4];
            const __hip_bfloat16* g0 = h0prev + (size_t)row0 * HID;
            const __hip_bfloat16* g1 = h0prev + (size_t)row1 * HID;
            const __hip_bfloat16* q0 = h1prev + (size_t)row0 * HID;
            const __hip_bfloat16* q1 = h1prev + (size_t)row1 * HID;

            auto load1 = [&](int j, int s) {
                const int ks = kq + 4 * j;
                Bs[s] = *(const bf16x8*)(lW1 + (size_t)(((ks * 4 + kg) * 16 + lm) * 8));
                const __hip_bfloat16* a0;
                const __hip_bfloat16* a1;
                int k;
                if (j < 8) { k = ks * 32 + kg * 8;        a0 = g0; a1 = g1; }
                else       { k = ks * 32 + kg * 8 - 1024; a0 = q0; a1 = q1; }
                if constexpr (FRESH) {
                    A0s[s] = load_bf16x8(a0 + k);
                    A1s[s] = load_bf16x8(a1 + k);
                } else {
                    A0s[s] = aload_bf16x8(a0 + k);
                    A1s[s] = aload_bf16x8(a1 + k);
                }
            };
            #pragma unroll
            for (int j = 0; j < 4; ++j) load1(j, j);
            #pragma unroll
            for (int j = 0; j < 16; ++j) {
                acc0 = mfma16(A0s[j & 3], Bs[j & 3], acc0);
                acc1 = mfma16(A1s[j & 3], Bs[j & 3], acc1);
                if (j < 12) load1(j + 4, j & 3);
            }
            #pragma unroll
            for (int r = 0; r < 4; ++r) {
                atomicAdd(&zacc[1][mq * 32 + kg * 4 + r][lm],      acc0[r]);
                atomicAdd(&zacc[1][mq * 32 + 16 + kg * 4 + r][lm], acc1[r]);
            }
        }
        __syncthreads();

        // ===== gates -> hstage (LDS) =====
        {
            const int L   = tid >> 9;
            const int idx = tid & 511;
            const int bl  = idx >> 2;
            const int u   = idx & 3;
            const bool act = L ? (p >= 1) : (p < SEQ);
            if (act) {
                float* zb = &zacc[L][bl][4 * u];
                const float zf = zb[0] + biasS[L][4 * u + 0];
                const float zi = zb[1] + biasS[L][4 * u + 1];
                const float zo = zb[2] + biasS[L][4 * u + 2];
                const float zg = zb[3] + biasS[L][4 * u + 3];
                zb[0] = 0.f; zb[1] = 0.f; zb[2] = 0.f; zb[3] = 0.f;
                const float cold = cS[L][idx];
                const float cn = sigmoidf_(zf) * cold + sigmoidf_(zi) * tanhf_(zg);
                const float hn = sigmoidf_(zo) * tanhf_(cn);
                cS[L][idx] = cn;
                hstage[L][bl][u] = __float2bfloat16(hn);
            }
        }
        __syncthreads();

        // ===== coalesced 8B bypass stores of h (straight to L3) =====
        if (tid < 256) {
            const int L  = tid >> 7;
            const int bl = tid & 127;
            const bool act = L ? (p >= 1) : (p < SEQ);
            if (act) {
                __hip_bfloat16* hw = L ? h1w : h0w;
                const u64 v = *(const u64*)&hstage[L][bl][0];
                __hip_atomic_store((u64*)(hw + (size_t)bl * HID + nb * 4), v,
                                   __ATOMIC_RELAXED, __HIP_MEMORY_SCOPE_AGENT);
            }
        }
        __syncthreads();   // all waves drain vmcnt -> stores visible at L3

        // ===== hierarchical grid barrier (bypass-atomic counters) =====
        if (tid == 0) {
            asm volatile("s_waitcnt vmcnt(0)" ::: "memory");
            int* grp = bar + 32 * (1 + (nb >> 5));
            __hip_atomic_fetch_add(grp, 1, __ATOMIC_RELAXED, __HIP_MEMORY_SCOPE_AGENT);
            if ((nb & 31) == 0) {
                const int gt = 32 * (p + 1);
                while (__hip_atomic_load(grp, __ATOMIC_RELAXED, __HIP_MEMORY_SCOPE_AGENT) < gt)
                    __builtin_amdgcn_s_sleep(1);
                __hip_atomic_fetch_add(bar, 1, __ATOMIC_RELAXED, __HIP_MEMORY_SCOPE_AGENT);
            }
            const int rt = 8 * (p + 1);
            while (__hip_atomic_load(bar, __ATOMIC_RELAXED, __HIP_MEMORY_SCOPE_AGENT) < rt)
                __builtin_amdgcn_s_sleep(1);
            // periodic cache-lifetime bound: ring reuse distance is 64 phases,
            // invalidate L1+L2 every 32 -> no stale line can survive to reuse.
            if constexpr (FRESH) {
                if ((p & 31) == 31)
                    __builtin_amdgcn_fence(__ATOMIC_ACQUIRE, "agent");
            }
            asm volatile("" ::: "memory");
        }
        __syncthreads();
    }

    // ---- head: out[b] = sigmoid(h1(511) . Wout + bout) ----
    if (nb == 0 && tid < BATCH) {
        const __hip_bfloat16* hr =
            h1r + (size_t)(SEQ - 1 < 0 ? 0 : ((SEQ - 1) & RMASK)) * HS + (size_t)tid * HID;
        float acc = 0.f;
        for (int k2 = 0; k2 < HID; k2 += 8) {
            bf16x8 v = FRESH ? load_bf16x8(hr + k2) : aload_bf16x8(hr + k2);
            #pragma unroll
            for (int j = 0; j < 8; ++j)
                acc += (float)v[j] * Wout[k2 + j];
        }
        out[tid] = 1.f / (1.f + __expf(-(acc + bout[0])));
    }
}

// ---------------------------------------------------------------------------
extern "C" void kernel_launch(void* const* d_in, const int* in_sizes, int n_in,
                              void* d_out, int out_size, void* d_ws, size_t ws_size,
                              hipStream_t stream)
{
    const float* x    = (const float*)d_in[0];
    const float* W0   = (const float*)d_in[1];
    const float* b0   = (const float*)d_in[2];
    const float* W1   = (const float*)d_in[3];
    const float* b1   = (const float*)d_in[4];
    const float* Wout = (const float*)d_in[5];
    const float* bout = (const float*)d_in[6];
    float* out = (float*)d_out;

    char* ws = (char*)d_ws;
    const size_t OFF_F0  = 0;            // 12,582,912
    const size_t OFF_F1  = 12582912;     // +16,777,216 -> 29,360,128
    const size_t OFF_B0R = 29360128;     // 16,384
    const size_t OFF_B1R = 29376512;     // 16,384
    const size_t OFF_BAR = 29392896;     // 4,096
    const size_t OFF_R0  = 29396992;     // rings start (4K aligned)
    const size_t SLOT    = 262144;       // one h generation: 128*1024*2B

    const size_t NEED_FRESH = OFF_R0 + 128 * SLOT;              // 62,951,424
    const bool fresh = (ws_size >= NEED_FRESH);
    const size_t OFF_R1 = fresh ? (OFF_R0 + 64 * SLOT) : (OFF_R0 + 2 * SLOT);
    const size_t OFF_XB = fresh ? NEED_FRESH : (OFF_R0 + 4 * SLOT);
    const size_t XBYTES = (size_t)BATCH * SEQ * INP * 2;        // 67,108,864
    const bool xbf = (ws_size >= OFF_XB + XBYTES);

    __hip_bfloat16* F0 = (__hip_bfloat16*)(ws + OFF_F0);
    __hip_bfloat16* F1 = (__hip_bfloat16*)(ws + OFF_F1);
    float* b0r = (float*)(ws + OFF_B0R);
    float* b1r = (float*)(ws + OFF_B1R);
    __hip_bfloat16* h0r = (__hip_bfloat16*)(ws + OFF_R0);
    __hip_bfloat16* h1r = (__hip_bfloat16*)(ws + OFF_R1);
    int* bar = (int*)(ws + OFF_BAR);
    __hip_bfloat16* xbp = (__hip_bfloat16*)(ws + OFF_XB);

    // per-call state reset (graph replays must be deterministic)
    hipMemsetAsync(ws + OFF_BAR, 0, 4096, stream);
    if (fresh) {
        // zero only the t = -1 slots (slot 63 of each ring)
        hipMemsetAsync(ws + OFF_R0 + 63 * SLOT, 0, SLOT, stream);
        hipMemsetAsync(ws + OFF_R1 + 63 * SLOT, 0, SLOT, stream);
    } else {
        hipMemsetAsync(ws + OFF_R0, 0, 4 * SLOT, stream);
    }

    pack_frag_kernel<KS0><<<dim3(48, 128), 1024, 0, stream>>>(W0, F0);
    pack_frag_kernel<KS1><<<dim3(64, 128), 1024, 0, stream>>>(W1, F1);
    bias_reorder_kernel<<<32, 256, 0, stream>>>(b0, b1, b0r, b1r);
    if (xbf)
        xconv_kernel<<<(BATCH * SEQ * INP) / (256 * 8), 256, 0, stream>>>(x, xbp);

    hipFuncSetAttribute((const void*)lstm_persistent<true,  true>,
                        hipFuncAttributeMaxDynamicSharedMemorySize, LDS_DYN);
    hipFuncSetAttribute((const void*)lstm_persistent<false, true>,
                        hipFuncAttributeMaxDynamicSharedMemorySize, LDS_DYN);
    hipFuncSetAttribute((const void*)lstm_persistent<true,  false>,
                        hipFuncAttributeMaxDynamicSharedMemorySize, LDS_DYN);
    hipFuncSetAttribute((const void*)lstm_persistent<false, false>,
                        hipFuncAttributeMaxDynamicSharedMemorySize, LDS_DYN);

    void* args[] = {(void*)&x, (void*)&xbp, (void*)&F0, (void*)&F1,
                    (void*)&b0r, (void*)&b1r, (void*)&Wout, (void*)&bout,
                    (void*)&h0r, (void*)&h1r, (void*)&out, (void*)&bar};
    const void* kfun = fresh
        ? (xbf ? (const void*)lstm_persistent<true,  true>
               : (const void*)lstm_persistent<false, true>)
        : (xbf ? (const void*)lstm_persistent<true,  false>
               : (const void*)lstm_persistent<false, false>);
    hipLaunchCooperativeKernel((void*)kfun, dim3(NB), dim3(1024),
                               args, LDS_DYN, stream);
}